// Round 5
// baseline (56.896 us; speedup 1.0000x reference)
//
#include <hip/hip_runtime.h>
#include <hip/hip_bf16.h>

// MaskedDenseLayerMultiMasks: out[b,m,o] = sum_i x[b,m,i] * kernel[i,o] * masks[m,i,o]
// bf16 MFMA GEMM, fused fp32->bf16 convert + mask-multiply during reg staging.
// Round 5: TRUE cross-barrier pipelining. Raw s_barrier + manual lgkmcnt(0)
// (no vmcnt drain -- __syncthreads would drain all loads, m97's ~20% stall).
// B stream (masks+kernel) gets a 2-deep register pipeline with two NAMED
// copies (static indexing, rule #20); loads for tile t+2 stay in flight
// across the barrier via compiler-derived counted vmcnt. A (L2-hot x) 1-deep.

#define BATCH 512
#define NMASK 16
#define IN_D  1024
#define OUT_D 1024

#define BM 128
#define BN 128
#define BK 32
#define NT (IN_D / BK)   // 32
#define AKP 40           // A LDS k-stride: 80B rows, b128 r/w at bank floor
#define BKP 34           // B LDS k-stride: 68B rows, b64 writes at bank floor
#define THREADS 512

using bf16x8  = __attribute__((ext_vector_type(8))) __bf16;
using bf16x4t = __attribute__((ext_vector_type(4))) __bf16;
using f32x4   = __attribute__((ext_vector_type(4))) float;
using f32x2   = __attribute__((ext_vector_type(2))) float;
using u16x8   = __attribute__((ext_vector_type(8))) unsigned short;
using u16x4   = __attribute__((ext_vector_type(4))) unsigned short;

__device__ __forceinline__ unsigned short f2bf(float f) {
    unsigned u = __float_as_uint(f);
    u += 0x7fffu + ((u >> 16) & 1u);          // RNE
    return (unsigned short)(u >> 16);
}

struct BRegs { f32x2 kv[4]; f32x2 mv[4]; };

__global__ void __launch_bounds__(THREADS, 4)
mdl_mfma_kernel(const float* __restrict__ X,   // (B, M, I)
                const float* __restrict__ Kn,  // (I, O)
                const float* __restrict__ Mk,  // (M, I, O)
                float* __restrict__ Out)       // (B, M, O)
{
    __shared__ __align__(16) unsigned short As[2][BM * AKP];
    __shared__ __align__(16) unsigned short Bs[2][BN * BKP];

    const int t = threadIdx.x;
    const int l = t & 63;
    const int w = t >> 6;          // wave 0..7

    // XCD-aware bijective swizzle: 512 wgs, 8 XCDs, 64 contiguous wgs/XCD.
    const int raw = blockIdx.x;
    const int wg  = (raw & 7) * 64 + (raw >> 3);
    const int m   = wg >> 5;          // 0..15
    const int ob  = (wg >> 2) & 7;    // 0..7
    const int bb  = wg & 3;           // 0..3

    const int wr = w >> 2;            // 0..1
    const int wc = w & 3;             // 0..3

    f32x4 acc[4][2];
#pragma unroll
    for (int mi = 0; mi < 4; ++mi)
#pragma unroll
        for (int ni = 0; ni < 2; ++ni)
            acc[mi][ni] = (f32x4){0.f, 0.f, 0.f, 0.f};

    // A staging: row = t/4, k-chunk = (t&3)*8
    const int a_row = t >> 2;
    const int a_k   = (t & 3) * 8;
    // B staging: 4i x 2o patch: o = 2*(t&63)+c, i = (t>>6)*4+r
    const int o_l = (t & 63) * 2;
    const int ig  = t >> 6;           // 0..7 (== w)
    const int i_l = ig * 4;

    const float* Xa  = X + ((size_t)(bb * BM + a_row) * NMASK + m) * IN_D + a_k;
    const float* Knb = Kn + (size_t)i_l * OUT_D + ob * BN + o_l;
    const float* Mkb = Mk + ((size_t)m * IN_D + i_l) * OUT_D + ob * BN + o_l;

    f32x4 av0, av1;      // A pipeline (1-deep)
    BRegs b0, b1;        // B pipeline (2-deep, named copies)

    auto LOADA = [&](int kt) {
        av0 = *(const f32x4*)(Xa + kt);
        av1 = *(const f32x4*)(Xa + kt + 4);
    };
    auto LOADB = [&](BRegs& bg, int kt) {
#pragma unroll
        for (int r = 0; r < 4; ++r) {
            bg.kv[r] = *(const f32x2*)(Knb + (size_t)(kt + r) * OUT_D);
            bg.mv[r] = *(const f32x2*)(Mkb + (size_t)(kt + r) * OUT_D);
        }
    };
    auto STORE = [&](int buf, BRegs& bg) {
        // B first: its loads are 1 iter old -> counted vmcnt leaves new loads in flight
#pragma unroll
        for (int c = 0; c < 2; ++c) {
            u16x4 v;
#pragma unroll
            for (int r = 0; r < 4; ++r) v[r] = f2bf(bg.kv[r][c] * bg.mv[r][c]);
            *(u16x4*)(&Bs[buf][(o_l + c) * BKP + ig * 4]) = v;
        }
        // A second: waits only on this iter's 2 A-loads (L2-hot, covered by MFMA)
        u16x8 va;
#pragma unroll
        for (int j = 0; j < 4; ++j) { va[j] = f2bf(av0[j]); va[4 + j] = f2bf(av1[j]); }
        *(u16x8*)(&As[buf][a_row * AKP + a_k]) = va;
    };
    auto MFMA_PHASE = [&](int buf) {
        const int kg = (l >> 4) * 8;
        bf16x8 bfv[2];
#pragma unroll
        for (int ni = 0; ni < 2; ++ni) {
            const int n = wc * 32 + ni * 16 + (l & 15);
            bf16x4t lo = *(const bf16x4t*)(&Bs[buf][n * BKP + kg]);
            bf16x4t hi = *(const bf16x4t*)(&Bs[buf][n * BKP + kg + 4]);
            bf16x8 f;
            f[0] = lo[0]; f[1] = lo[1]; f[2] = lo[2]; f[3] = lo[3];
            f[4] = hi[0]; f[5] = hi[1]; f[6] = hi[2]; f[7] = hi[3];
            bfv[ni] = f;
        }
#pragma unroll
        for (int mi = 0; mi < 4; ++mi) {
            const int r = wr * 64 + mi * 16 + (l & 15);
            bf16x8 af = *(const bf16x8*)(&As[buf][r * AKP + kg]);
#pragma unroll
            for (int ni = 0; ni < 2; ++ni)
                acc[mi][ni] = __builtin_amdgcn_mfma_f32_16x16x32_bf16(
                    af, bfv[ni], acc[mi][ni], 0, 0, 0);
        }
    };
    auto BARRIER = [&]() {
        asm volatile("s_waitcnt lgkmcnt(0)" ::: "memory");  // ds_writes visible
        __builtin_amdgcn_sched_barrier(0);
        __builtin_amdgcn_s_barrier();                       // NO vmcnt drain
        __builtin_amdgcn_sched_barrier(0);
    };

    // ---- prologue: tile0 -> buf0; tile1 loads in flight ----
    LOADA(0);
    LOADB(b0, 0);
    STORE(0, b0);
    LOADB(b1, BK);
    BARRIER();

    // ---- main loop, 2x unrolled for static b0/b1 roles; 1 barrier/iter ----
    for (int tt = 0; tt < NT; tt += 2) {
        // even: compute buf0 (tile tt); store tile tt+1 -> buf1 from b1
        if (tt + 1 < NT) LOADA((tt + 1) * BK);
        if (tt + 2 < NT) LOADB(b0, (tt + 2) * BK);
        __builtin_amdgcn_sched_barrier(0);
        MFMA_PHASE(0);
        if (tt + 1 < NT) STORE(1, b1);
        BARRIER();
        // odd: compute buf1 (tile tt+1); store tile tt+2 -> buf0 from b0
        if (tt + 2 < NT) LOADA((tt + 2) * BK);
        if (tt + 3 < NT) LOADB(b1, (tt + 3) * BK);
        __builtin_amdgcn_sched_barrier(0);
        MFMA_PHASE(1);
        if (tt + 2 < NT) STORE(0, b0);
        BARRIER();
    }

    // ---- epilogue: C/D layout col = l&15, row = (l>>4)*4 + reg ----
    const int r0 = bb * BM + wr * 64 + (l >> 4) * 4;
    const int c0 = ob * BN + wc * 32 + (l & 15);
#pragma unroll
    for (int mi = 0; mi < 4; ++mi) {
#pragma unroll
        for (int j = 0; j < 4; ++j) {
            const size_t row = (size_t)(r0 + mi * 16 + j);
            float* op = Out + (row * NMASK + m) * OUT_D + c0;
#pragma unroll
            for (int ni = 0; ni < 2; ++ni)
                op[ni * 16] = acc[mi][ni][j];
        }
    }
}

extern "C" void kernel_launch(void* const* d_in, const int* in_sizes, int n_in,
                              void* d_out, int out_size, void* d_ws, size_t ws_size,
                              hipStream_t stream) {
    (void)in_sizes; (void)n_in; (void)d_ws; (void)ws_size; (void)out_size;
    const float* X  = (const float*)d_in[0];
    const float* Kn = (const float*)d_in[1];
    const float* Mk = (const float*)d_in[2];
    float* Out = (float*)d_out;

    const int nblocks = (BATCH / BM) * (OUT_D / BN) * NMASK;  // 512
    mdl_mfma_kernel<<<nblocks, THREADS, 0, stream>>>(X, Kn, Mk, Out);
}